// Round 6
// baseline (585.247 us; speedup 1.0000x reference)
//
#include <hip/hip_runtime.h>

#define K_DIM 128

typedef __attribute__((ext_vector_type(8))) short short8;
typedef __attribute__((ext_vector_type(4))) float f32x4;

// ---- compile-time path tables: PATHS order = l1-major, l2, l3 ascending ----
constexpr int C_L1[34] = {0,0,0,0, 1,1,1,1,1,1,1,1,1, 2,2,2,2,2,2,2,2,2,2,2, 3,3,3,3,3,3,3,3,3,3};
constexpr int C_L2[34] = {0,1,2,3, 0,1,1,1,2,2,2,3,3, 0,1,1,1,2,2,2,2,3,3,3, 0,1,1,2,2,2,3,3,3,3};
constexpr int C_L3[34] = {0,1,2,3, 1,0,1,2,1,2,3,2,3, 2,1,2,3,0,1,2,3,1,2,3, 3,2,3,1,2,3,0,1,2,3};
constexpr int C_NP[4]  = {4,9,11,10};
constexpr int C_PL[4][11] = {
  {0,5,17,30, 0,0,0,0,0,0,0},
  {1,4,6,8,14,18,21,27,31, 0,0},
  {2,7,9,11,13,15,19,22,25,28,32},
  {3,10,12,16,20,23,24,26,29,33, 0}
};
constexpr int C_CSUM[4] = {0,8,26,48};      // 64-ch chunk base per l3
constexpr size_t FOFF[4] = {0, 1048576, 4194304, 9437184};  // per-l elem offsets
constexpr int FSZ[4] = {1048576, 3145728, 5242880, 7340032};
constexpr size_t FTOT = 16777216;           // elems per f-set

__device__ double dfactd(int n){ double r=1.0; for(int i=2;i<=n;++i) r*=(double)i; return r; }

__device__ __forceinline__ unsigned short f2bf(float x) {
    unsigned int b = __float_as_uint(x);
    return (unsigned short)((b + 0x7FFFu + ((b >> 16) & 1u)) >> 16);
}

// packed RNE f32x2 -> bf16x2 (single VALU inst; pure-ALU asm, no mem hazard)
__device__ __forceinline__ unsigned int cvtpk(float lo, float hi) {
    unsigned int r;
    asm("v_cvt_pk_bf16_f32 %0, %1, %2" : "=v"(r) : "v"(lo), "v"(hi));
    return r;
}

// async global->LDS, 16B per lane (no VGPR round-trip)
__device__ __forceinline__ void gload_lds16(const void* g, void* l) {
    __builtin_amdgcn_global_load_lds(
        (const __attribute__((address_space(1))) void*)g,
        (__attribute__((address_space(3))) void*)l, 16, 0, 0);
}

// C2[p][m1i][m2i], 34*49 floats at d_ws+0
__global__ void cg_init(float* __restrict__ C2) {
    int e = blockIdx.x*blockDim.x + threadIdx.x;
    if (e >= 34*49) return;
    int p = e/49, r = e%49, m1i = r/7, m2i = r%7;
    int l1 = C_L1[p], l2 = C_L2[p], l3 = C_L3[p];
    float val = 0.f;
    if (m1i < 2*l1+1 && m2i < 2*l2+1) {
        int m1 = m1i-l1, m2 = m2i-l2, m3 = m1+m2;
        if (m3 >= -l3 && m3 <= l3) {
            double pref = sqrt((double)(2*l3+1) * dfactd(l3+l1-l2)*dfactd(l3-l1+l2)
                               * dfactd(l1+l2-l3) / dfactd(l1+l2+l3+1));
            pref *= sqrt(dfactd(l3+m3)*dfactd(l3-m3)*dfactd(l1-m1)*dfactd(l1+m1)
                         *dfactd(l2-m2)*dfactd(l2+m2));
            int kmin = max(0, max(l2-l3-m1, l1-l3+m2));
            int kmax = min(l1+l2-l3, min(l1-m1, l2+m2));
            double s = 0.0;
            for (int k=kmin;k<=kmax;++k) {
                double t = dfactd(k)*dfactd(l1+l2-l3-k)*dfactd(l1-m1-k)
                         * dfactd(l2+m2-k)*dfactd(l3-l2+m1+k)*dfactd(l3-l1-m2+k);
                s += ((k&1)? -1.0:1.0)/t;
            }
            val = (float)(pref*s);
        }
    }
    C2[e] = val;
}

// W -> bf16 transposed+swizzled tiles
__global__ void wt_prep(const float* __restrict__ W0, const float* __restrict__ W1,
                        const float* __restrict__ W2, const float* __restrict__ W3,
                        unsigned short* __restrict__ wt) {
    int b = blockIdx.x;
    int chunk = b >> 5;
    int e = ((b & 31) << 8) + threadIdx.x;
    int kk = e & 63, col = e >> 6;
    int l3 = (chunk < 8) ? 0 : (chunk < 26) ? 1 : (chunk < 48) ? 2 : 3;
    int local = chunk - C_CSUM[l3];
    int kin = local*64 + kk;
    const float* W = (l3==0)?W0:(l3==1)?W1:(l3==2)?W2:W3;
    float v = W[(size_t)kin*K_DIM + col];
    wt[(size_t)chunk*8192 + col*64 + (kk ^ ((col&7)<<3))] = f2bf(v);
}

// f1/f2 -> bf16 packed copies in ws
__global__ void fpack(const float* __restrict__ s0, const float* __restrict__ s1,
                      const float* __restrict__ s2, const float* __restrict__ s3,
                      const float* __restrict__ s4, const float* __restrict__ s5,
                      const float* __restrict__ s6, const float* __restrict__ s7,
                      unsigned short* __restrict__ dst) {
    int y = blockIdx.y;
    int l = y & 3, fi = y >> 2;
    const float* srcs[8] = {s0,s1,s2,s3,s4,s5,s6,s7};
    const float* src = srcs[y];
    int i4 = blockIdx.x*256 + threadIdx.x;
    if (i4*4 >= FSZ[l]) return;
    float4 v = reinterpret_cast<const float4*>(src)[i4];
    unsigned int u0 = (unsigned int)f2bf(v.x) | ((unsigned int)f2bf(v.y) << 16);
    unsigned int u1 = (unsigned int)f2bf(v.z) | ((unsigned int)f2bf(v.w) << 16);
    unsigned short* d = dst + fi*FTOT + FOFF[l] + (size_t)i4*4;
    *reinterpret_cast<uint2*>(d) = make_uint2(u0, u1);
}

#define DO_DW(i, u, v) { \
    float x0 = __uint_as_float((u)<<16); \
    float x1 = __uint_as_float((u)&0xFFFF0000u); \
    float y0 = __uint_as_float((v)<<16); \
    float y1 = __uint_as_float((v)&0xFFFF0000u); \
    a[2*(i)]   = fmaf(c*x0, y0, a[2*(i)]); \
    a[2*(i)+1] = fmaf(c*x1, y1, a[2*(i)+1]); }

// One (path, h) pair: async W stage, batched TP loads -> compute -> A tile, MFMA.
template<int L3, int PI>
__device__ __forceinline__ void chunk_pair(
    const unsigned short* __restrict__ f1b, const unsigned short* __restrict__ f2b,
    const unsigned short* __restrict__ wt, const float* __restrict__ C2,
    float* C2s, unsigned char* Asb, unsigned char* Wtb,
    int tid, int n, int m3, int r, int chq,
    int wid, int lr, int lg, f32x4 (&acc)[8])
{
    constexpr int P  = C_PL[L3][PI];
    constexpr int l1 = C_L1[P], l2 = C_L2[P];
    constexpr int d1 = 2*l1+1, d2 = 2*l2+1;

    if (tid < 49) C2s[tid] = C2[P*49 + tid];

    #pragma unroll
    for (int h = 0; h < 2; ++h) {
        __syncthreads();   // prev MFMA done reading Asb/Wtb; C2s visible
        // ---- async W-tile stage: 16KB via LDS-DMA (no VGPR cost) ----
        {
            const char* wsrc = (const char*)(wt + (size_t)(C_CSUM[L3] + PI*2 + h) * 8192);
            gload_lds16(wsrc + tid*16,        Wtb + tid*16);
            gload_lds16(wsrc + 8192 + tid*16, Wtb + 8192 + tid*16);
        }
        // ---- TP: batched unconditional loads (index-clamped), then compute ----
        const unsigned short* bp1 = f1b + FOFF[l1] + (size_t)n*(d1*128) + h*64 + chq;
        const unsigned short* bp2 = f2b + FOFF[l2] + (size_t)n*(d2*128) + h*64 + chq;
        float cf[d1];
        uint4 qa[d1], qb[d1], ra[d1], rb[d1];
        #pragma unroll
        for (int m1i=0; m1i<d1; ++m1i) {
            int m2i = m3 + (l1 + l2) - m1i;
            bool ok = (m2i >= 0) && (m2i < d2);
            int m2c = ok ? m2i : 0;
            cf[m1i] = ok ? C2s[m1i*7 + m2i] : 0.f;
            qa[m1i] = *reinterpret_cast<const uint4*>(bp1 + m1i*128);
            qb[m1i] = *reinterpret_cast<const uint4*>(bp1 + m1i*128 + 8);
            ra[m1i] = *reinterpret_cast<const uint4*>(bp2 + m2c*128);
            rb[m1i] = *reinterpret_cast<const uint4*>(bp2 + m2c*128 + 8);
        }
        float a[16];
        #pragma unroll
        for (int j=0;j<16;++j) a[j] = 0.f;
        #pragma unroll
        for (int m1i=0; m1i<d1; ++m1i) {
            float c = cf[m1i];
            DO_DW(0, qa[m1i].x, ra[m1i].x)  DO_DW(1, qa[m1i].y, ra[m1i].y)
            DO_DW(2, qa[m1i].z, ra[m1i].z)  DO_DW(3, qa[m1i].w, ra[m1i].w)
            DO_DW(4, qb[m1i].x, rb[m1i].x)  DO_DW(5, qb[m1i].y, rb[m1i].y)
            DO_DW(6, qb[m1i].z, rb[m1i].z)  DO_DW(7, qb[m1i].w, rb[m1i].w)
        }
        // pack to bf16 (v_cvt_pk) + swizzled LDS write (2 x b128)
        unsigned int pk[8];
        #pragma unroll
        for (int j=0;j<8;++j) pk[j] = cvtpk(a[2*j], a[2*j+1]);
        {
            int ab = r*128, g0 = chq*2, key = (r&7)<<4;
            *reinterpret_cast<uint4*>(Asb + ab + ( g0        ^ key)) = make_uint4(pk[0],pk[1],pk[2],pk[3]);
            *reinterpret_cast<uint4*>(Asb + ab + ((g0 + 16)  ^ key)) = make_uint4(pk[4],pk[5],pk[6],pk[7]);
        }
        __syncthreads();   // drains vmcnt (W LDS-DMA) + lgkm; tiles ready
        // ---- MFMA: 2 K=32 steps, 1 row-tile x 8 col-tiles per wave ----
        #pragma unroll
        for (int ks=0; ks<2; ++ks) {
            const int kb = 16*lg + 64*ks;
            const int arow = 16*wid + lr;
            short8 af = *reinterpret_cast<const short8*>(
                Asb + arow*128 + (kb ^ ((arow&7)<<4)));
            #pragma unroll
            for (int cc=0; cc<8; ++cc) {
                int col = 16*cc + lr;
                short8 bf = *reinterpret_cast<const short8*>(
                    Wtb + col*128 + (kb ^ ((col&7)<<4)));
                acc[cc] = __builtin_amdgcn_mfma_f32_16x16x32_bf16(af, bf, acc[cc], 0, 0, 0);
            }
        }
    }
}

template<int L3, int PI>
__device__ __forceinline__ void paths_from(
    const unsigned short* __restrict__ f1b, const unsigned short* __restrict__ f2b,
    const unsigned short* __restrict__ wt, const float* __restrict__ C2,
    float* C2s, unsigned char* Asb, unsigned char* Wtb,
    int tid, int n, int m3, int r, int chq,
    int wid, int lr, int lg, f32x4 (&acc)[8])
{
    if constexpr (PI < C_NP[L3]) {
        chunk_pair<L3, PI>(f1b, f2b, wt, C2, C2s, Asb, Wtb,
                           tid, n, m3, r, chq, wid, lr, lg, acc);
        paths_from<L3, PI+1>(f1b, f2b, wt, C2, C2s, Asb, Wtb,
                             tid, n, m3, r, chq, wid, lr, lg, acc);
    }
}

template<int L3>
__device__ __forceinline__ void run_l3(
    int rb,
    const unsigned short* __restrict__ f1b, const unsigned short* __restrict__ f2b,
    const unsigned short* __restrict__ wt, const float* __restrict__ C2,
    float* __restrict__ out,
    float* C2s, unsigned char* Asb, unsigned char* Wtb)
{
    constexpr int TL3 = 2*L3+1;
    const int tid = threadIdx.x;
    const int row0 = rb*128;
    const int r   = tid >> 2;          // TP row 0..127
    const int chq = (tid & 3) * 16;    // TP ch base within 64-half
    const int gr  = row0 + r;
    const int n   = gr / TL3;
    const int m3  = (gr - n*TL3) - L3;
    const int lane = tid & 63, wid = tid >> 6;
    const int lr = lane & 15, lg = lane >> 4;
    constexpr size_t OB = FOFF[L3];

    f32x4 acc[8];
    #pragma unroll
    for (int c=0;c<8;++c) acc[c] = (f32x4){0.f,0.f,0.f,0.f};

    paths_from<L3, 0>(f1b, f2b, wt, C2, C2s, Asb, Wtb,
                      tid, n, m3, r, chq, wid, lr, lg, acc);

    // epilogue: residual (bf16 f1) + store. D: col=lane&15, row=4*(lane>>4)+i
    const unsigned short* __restrict__ fr = f1b + OB;
    #pragma unroll
    for (int i=0;i<4;++i) {
        int rr = 16*wid + 4*lg + i;
        size_t ro = (size_t)(row0 + rr) * K_DIM;
        #pragma unroll
        for (int cc=0;cc<8;++cc) {
            int col = 16*cc + lr;
            float res = __uint_as_float((unsigned int)fr[ro + col] << 16);
            out[OB + ro + col] = res + acc[cc][i];
        }
    }
}

__global__ __launch_bounds__(512) void cg_main(
    const unsigned short* __restrict__ f1b, const unsigned short* __restrict__ f2b,
    const unsigned short* __restrict__ wt,
    const float* __restrict__ C2, float* __restrict__ out)
{
    __shared__ __align__(16) unsigned char Asb[128*128];
    __shared__ __align__(16) unsigned char Wtb[128*128];
    __shared__ float C2s[49];

    // XCD-aware remap: bid%8 = XCD (round-robin). Give each XCD the blocks of
    // ALL l3 groups covering the same node slice n in [1024x, 1024(x+1)).
    int bid = blockIdx.x;
    int x = bid & 7, j = bid >> 3;
    if (j < 8)
        run_l3<0>(x*8  + j,      f1b, f2b, wt, C2, out, C2s, Asb, Wtb);
    else if (j < 32)
        run_l3<1>(x*24 + (j-8),  f1b, f2b, wt, C2, out, C2s, Asb, Wtb);
    else if (j < 72)
        run_l3<2>(x*40 + (j-32), f1b, f2b, wt, C2, out, C2s, Asb, Wtb);
    else
        run_l3<3>(x*56 + (j-72), f1b, f2b, wt, C2, out, C2s, Asb, Wtb);
}

extern "C" void kernel_launch(void* const* d_in, const int* in_sizes, int n_in,
                              void* d_out, int out_size, void* d_ws, size_t ws_size,
                              hipStream_t stream) {
    const float* f10 = (const float*)d_in[0];
    const float* f20 = (const float*)d_in[1];
    const float* W0  = (const float*)d_in[2];
    const float* f11 = (const float*)d_in[3];
    const float* f21 = (const float*)d_in[4];
    const float* W1  = (const float*)d_in[5];
    const float* f12 = (const float*)d_in[6];
    const float* f22 = (const float*)d_in[7];
    const float* W2  = (const float*)d_in[8];
    const float* f13 = (const float*)d_in[9];
    const float* f23 = (const float*)d_in[10];
    const float* W3  = (const float*)d_in[11];

    float* C2 = (float*)d_ws;                                       // 6664 B
    unsigned short* wtw = (unsigned short*)((char*)d_ws + 8192);    // 1.09 MB
    unsigned short* f1b = (unsigned short*)((char*)d_ws + 1122304); // 32 MB
    unsigned short* f2b = f1b + FTOT;                               // 32 MB
    float* out = (float*)d_out;

    hipLaunchKernelGGL(cg_init, dim3(7), dim3(256), 0, stream, C2);
    hipLaunchKernelGGL(wt_prep, dim3(68*32), dim3(256), 0, stream, W0, W1, W2, W3, wtw);
    hipLaunchKernelGGL(fpack, dim3(7168, 8), dim3(256), 0, stream,
        f10, f11, f12, f13, f20, f21, f22, f23, f1b);
    hipLaunchKernelGGL(cg_main, dim3(1024), dim3(512), 0, stream,
        f1b, f2b, wtw, C2, out);
}